// Round 9
// baseline (74.165 us; speedup 1.0000x reference)
//
#include <hip/hip_runtime.h>
#include <hip/hip_bf16.h>

typedef __bf16 bf16x8 __attribute__((ext_vector_type(8)));
typedef float f32x4 __attribute__((ext_vector_type(4)));

#define NB 8
#define NH 128
#define NWID 128
#define NC 32
#define NO 32
#define NPTS 9
#define KPAD 296      // sW row stride in halves (R2/R4-verified bank layout)
#define PB 64         // pixels per block (4 waves x 16)

__global__ __launch_bounds__(256, 2)
void dcn_kernel(const float* __restrict__ x,
                const float* __restrict__ off,
                const float* __restrict__ Wsrc,
                const float* __restrict__ bias,
                float* __restrict__ out)
{
    __shared__ __hip_bfloat16 sW[NO][KPAD];

    const int tid = threadIdx.x;

    // ---- stage W with slot->channel map sigma (forward map, used ONLY here):
    // slot s holds channel sigma(s) = ((s&4)<<2) + ((s>>3)<<2) + (s&3).
    // Matches the A-side: lane cq's GLD0 (line 0) supplies channels 4cq..4cq+3
    // to slots 8cq..8cq+3; GLD1 (line 1) supplies 16+4cq..16+4cq+3 to slots
    // 8cq+4..8cq+7.  sigma(8cq+j)=4cq+j, sigma(8cq+4+j)=16+4cq+j. Bijective.
    for (int idx = tid; idx < NPTS * NC * NO; idx += 256) {
        int n = idx >> 10;
        int s = (idx >> 5) & 31;
        int o = idx & 31;
        int c = ((s & 4) << 2) + ((s >> 3) << 2) + (s & 3);
        sW[o][(n << 5) + s] = __float2bfloat16(Wsrc[(n << 10) + (c << 5) + o]);
    }
    __syncthreads();

    // XCD swizzle (R4: FETCH 110->13MB): one image per XCD, L2-resident.
    const int lb = ((blockIdx.x & 7) << 8) | (blockIdx.x >> 3);
    const int pix0 = lb * PB;

    const int wave = tid >> 6;
    const int lane = tid & 63;
    const int row  = lane & 15;   // pixel within wave tile == A-frag row == B col
    const int cq   = lane >> 4;   // lane's channel sub-group
    const int gp   = pix0 + (wave << 4) + row;
    const int bidx = gp >> 14;    // uniform per wave (16 consecutive px, one image)
    const int hh   = (gp >> 7) & 127;
    const int ww   = gp & 127;
    const float* xb = x + ((size_t)bidx << 19);   // wave-uniform image base
    const int cqb  = cq << 4;                     // cq*16 BYTES: lanes of one pixel
                                                  // cover ONE 64B line per instr
    const float* offp = off + (size_t)gp * 18;

    // TF-quirk init_off (R2-verified): pairs formed ACROSS the ii/jj boundary
    const int ioff0[9] = {0,0,1,2,2,1,0,2,1};
    const int ioff1[9] = {0,1,1,2,0,2,1,0,2};

    // ---- precompute ALL corner byte-voffsets + fracs ----
    int vo_lt[9], vo_rt[9], vo_lb[9], vo_rb[9];
    float pf0[9], pf1[9];
    #pragma unroll
    for (int n = 0; n < 9; ++n) {
        float2 ovn = *reinterpret_cast<const float2*>(offp + 2 * n);
        float c0 = fminf(fmaxf((float)(hh - 1 + ioff0[n]) + ovn.x, 0.f), 127.f);
        float c1 = fminf(fmaxf((float)(ww - 1 + ioff1[n]) + ovn.y, 0.f), 127.f);
        float fl0 = floorf(c0), fl1 = floorf(c1);
        int lt0 = (int)fl0, lt1 = (int)fl1;
        int rb0 = (int)ceilf(c0), rb1 = (int)ceilf(c1);
        pf0[n] = c0 - fl0;
        pf1[n] = c1 - fl1;
        // byte offset: pixel_index*128B + cq*16B
        vo_lt[n] = (((lt0 << 7) + lt1) << 7) + cqb;
        vo_rt[n] = (((rb0 << 7) + lt1) << 7) + cqb;
        vo_lb[n] = (((lt0 << 7) + rb1) << 7) + cqb;
        vo_rb[n] = (((rb0 << 7) + rb1) << 7) + cqb;
    }

    f32x4 acc0 = {0.f, 0.f, 0.f, 0.f};
    f32x4 acc1 = {0.f, 0.f, 0.f, 0.f};

    // depth-2 asm pipeline: D[slot][lt_a,lt_b,rt_a,rt_b,lb_a,lb_b,rb_a,rb_b]
    // _a = line 0 (channels 4cq..4cq+3), _b = line 1 (channels 16+4cq..16+4cq+3)
    f32x4 D[2][8];

#define GLD0(dst, vof) asm volatile("global_load_dwordx4 %0, %1, %2" \
        : "=v"(dst) : "v"(vof), "s"(xb));
#define GLD1(dst, vof) asm volatile("global_load_dwordx4 %0, %1, %2 offset:64" \
        : "=v"(dst) : "v"(vof), "s"(xb));

#define ISSUE(S, N) \
        GLD0(D[S][0], vo_lt[N]) GLD1(D[S][1], vo_lt[N]) \
        GLD0(D[S][2], vo_rt[N]) GLD1(D[S][3], vo_rt[N]) \
        GLD0(D[S][4], vo_lb[N]) GLD1(D[S][5], vo_lb[N]) \
        GLD0(D[S][6], vo_rb[N]) GLD1(D[S][7], vo_rb[N])

#define CONSUME(S, N) {                                                        \
        float f0 = pf0[N], f1 = pf1[N];                                        \
        union { bf16x8 v; __hip_bfloat16 h[8]; } au;                           \
        _Pragma("unroll")                                                      \
        for (int j = 0; j < 4; ++j) {                                          \
            float t = D[S][0][j] + (D[S][2][j] - D[S][0][j]) * f0;             \
            float b = D[S][4][j] + (D[S][6][j] - D[S][4][j]) * f0;             \
            au.h[j] = __float2bfloat16(t + (b - t) * f1);                      \
        }                                                                      \
        _Pragma("unroll")                                                      \
        for (int j = 0; j < 4; ++j) {                                          \
            float t = D[S][1][j] + (D[S][3][j] - D[S][1][j]) * f0;             \
            float b = D[S][5][j] + (D[S][7][j] - D[S][5][j]) * f0;             \
            au.h[4 + j] = __float2bfloat16(t + (b - t) * f1);                  \
        }                                                                      \
        const int kk = ((N) << 5) + (cq << 3);                                 \
        bf16x8 b0 = *reinterpret_cast<const bf16x8*>(&sW[row][kk]);            \
        bf16x8 b1 = *reinterpret_cast<const bf16x8*>(&sW[row + 16][kk]);       \
        acc0 = __builtin_amdgcn_mfma_f32_16x16x32_bf16(au.v, b0, acc0, 0, 0, 0); \
        acc1 = __builtin_amdgcn_mfma_f32_16x16x32_bf16(au.v, b1, acc1, 0, 0, 0); \
    }

    ISSUE(0, 0)
    ISSUE(1, 1)
    #pragma unroll
    for (int n = 0; n < 9; ++n) {
        // FIFO: 16 outstanding; vmcnt(8) -> point n complete, n+1 in flight.
        if (n < 8) { asm volatile("s_waitcnt vmcnt(8)" ::: "memory"); }
        else       { asm volatile("s_waitcnt vmcnt(0)" ::: "memory"); }
        __builtin_amdgcn_sched_barrier(0);   // rule #18: pin consumers below waitcnt
        CONSUME(n & 1, n)
        if (n < 7) { ISSUE(n & 1, n + 2) }   // refill the slot just consumed
    }
#undef ISSUE
#undef CONSUME
#undef GLD0
#undef GLD1

    // ---- epilogue: C/D layout col=lane&15, row=(lane>>4)*4+i (R4-verified) ----
    const float bias0 = bias[row];
    const float bias1 = bias[row + 16];
    const int rbase = (wave << 4) + (cq << 2);
    #pragma unroll
    for (int i = 0; i < 4; ++i) {
        float* op = out + (size_t)(pix0 + rbase + i) * NO;
        op[row]      = acc0[i] + bias0;
        op[row + 16] = acc1[i] + bias1;
    }
}

extern "C" void kernel_launch(void* const* d_in, const int* in_sizes, int n_in,
                              void* d_out, int out_size, void* d_ws, size_t ws_size,
                              hipStream_t stream) {
    const float* x    = (const float*)d_in[0];
    const float* off  = (const float*)d_in[1];
    const float* Wsrc = (const float*)d_in[2];
    const float* bias = (const float*)d_in[3];
    float* out = (float*)d_out;
    const int npix = NB * NH * NWID;          // 131072
    dcn_kernel<<<npix / PB, 256, 0, stream>>>(x, off, Wsrc, bias, out);
}

// Round 10
// 73.422 us; speedup vs baseline: 1.0101x; 1.0101x over previous
//
#include <hip/hip_runtime.h>
#include <hip/hip_bf16.h>

typedef __bf16 bf16x8 __attribute__((ext_vector_type(8)));
typedef float f32x4 __attribute__((ext_vector_type(4)));

#define NB 8
#define NH 128
#define NWID 128
#define NC 32
#define NO 32
#define NPTS 9
#define KPAD 296      // sW row stride in halves (R2/R4-verified bank layout)
#define PB 64         // pixels per block (4 waves x 16)

// (256,1): permit 1 wave/EU -> VGPR budget up to 512. The R6-R9 plateau was the
// allocator spilling the 16-deep load pipeline to scratch to chase the
// LDS-permitted 8 waves/EU (64-VGPR budget). We trade occupancy for a REAL
// register-resident pipeline.
__global__ __launch_bounds__(256, 1)
void dcn_kernel(const float* __restrict__ x,
                const float* __restrict__ off,
                const float* __restrict__ Wsrc,
                const float* __restrict__ bias,
                float* __restrict__ out)
{
    __shared__ __hip_bfloat16 sW[NO][KPAD];

    const int tid = threadIdx.x;

    // ---- stage W with slot->channel map sigma (R9-verified):
    // sigma(s) = ((s&4)<<2) + ((s>>3)<<2) + (s&3)
    for (int idx = tid; idx < NPTS * NC * NO; idx += 256) {
        int n = idx >> 10;
        int s = (idx >> 5) & 31;
        int o = idx & 31;
        int c = ((s & 4) << 2) + ((s >> 3) << 2) + (s & 3);
        sW[o][(n << 5) + s] = __float2bfloat16(Wsrc[(n << 10) + (c << 5) + o]);
    }
    __syncthreads();

    // XCD swizzle (R4: FETCH 110->13MB): one image per XCD, L2-resident.
    const int lb = ((blockIdx.x & 7) << 8) | (blockIdx.x >> 3);
    const int pix0 = lb * PB;

    const int wave = tid >> 6;
    const int lane = tid & 63;
    const int row  = lane & 15;   // pixel within wave tile == A-frag row == B col
    const int cq   = lane >> 4;   // lane's channel sub-group
    const int gp   = pix0 + (wave << 4) + row;
    const int bidx = gp >> 14;    // uniform per wave (16 consecutive px, one image)
    const int hh   = (gp >> 7) & 127;
    const int ww   = gp & 127;
    const float* xb = x + ((size_t)bidx << 19);   // wave-uniform image base
    const int cqb  = cq << 4;                     // cq*16B: one 64B line per instr
    const float* offp = off + (size_t)gp * 18;

    // TF-quirk init_off (R2-verified): pairs formed ACROSS the ii/jj boundary
    const int ioff0[9] = {0,0,1,2,2,1,0,2,1};
    const int ioff1[9] = {0,1,1,2,0,2,1,0,2};

    // ---- precompute ALL corner byte-voffsets + fracs (keeps plain vmem loads
    //      fully drained before the asm pipeline starts) ----
    int vo_lt[9], vo_rt[9], vo_lb[9], vo_rb[9];
    float pf0[9], pf1[9];
    #pragma unroll
    for (int n = 0; n < 9; ++n) {
        float2 ovn = *reinterpret_cast<const float2*>(offp + 2 * n);
        float c0 = fminf(fmaxf((float)(hh - 1 + ioff0[n]) + ovn.x, 0.f), 127.f);
        float c1 = fminf(fmaxf((float)(ww - 1 + ioff1[n]) + ovn.y, 0.f), 127.f);
        float fl0 = floorf(c0), fl1 = floorf(c1);
        int lt0 = (int)fl0, lt1 = (int)fl1;
        int rb0 = (int)ceilf(c0), rb1 = (int)ceilf(c1);
        pf0[n] = c0 - fl0;
        pf1[n] = c1 - fl1;
        vo_lt[n] = (((lt0 << 7) + lt1) << 7) + cqb;
        vo_rt[n] = (((rb0 << 7) + lt1) << 7) + cqb;
        vo_lb[n] = (((lt0 << 7) + rb1) << 7) + cqb;
        vo_rb[n] = (((rb0 << 7) + rb1) << 7) + cqb;
    }

    f32x4 acc0 = {0.f, 0.f, 0.f, 0.f};
    f32x4 acc1 = {0.f, 0.f, 0.f, 0.f};

    // depth-2 asm pipeline: D[slot][lt_a,lt_b,rt_a,rt_b,lb_a,lb_b,rb_a,rb_b]
    f32x4 D[2][8];

#define GLD0(dst, vof) asm volatile("global_load_dwordx4 %0, %1, %2" \
        : "=v"(dst) : "v"(vof), "s"(xb));
#define GLD1(dst, vof) asm volatile("global_load_dwordx4 %0, %1, %2 offset:64" \
        : "=v"(dst) : "v"(vof), "s"(xb));

#define ISSUE(S, N) \
        GLD0(D[S][0], vo_lt[N]) GLD1(D[S][1], vo_lt[N]) \
        GLD0(D[S][2], vo_rt[N]) GLD1(D[S][3], vo_rt[N]) \
        GLD0(D[S][4], vo_lb[N]) GLD1(D[S][5], vo_lb[N]) \
        GLD0(D[S][6], vo_rb[N]) GLD1(D[S][7], vo_rb[N])

#define CONSUME(S, N) {                                                        \
        float f0 = pf0[N], f1 = pf1[N];                                        \
        union { bf16x8 v; __hip_bfloat16 h[8]; } au;                           \
        _Pragma("unroll")                                                      \
        for (int j = 0; j < 4; ++j) {                                          \
            float t = D[S][0][j] + (D[S][2][j] - D[S][0][j]) * f0;             \
            float b = D[S][4][j] + (D[S][6][j] - D[S][4][j]) * f0;             \
            au.h[j] = __float2bfloat16(t + (b - t) * f1);                      \
        }                                                                      \
        _Pragma("unroll")                                                      \
        for (int j = 0; j < 4; ++j) {                                          \
            float t = D[S][1][j] + (D[S][3][j] - D[S][1][j]) * f0;             \
            float b = D[S][5][j] + (D[S][7][j] - D[S][5][j]) * f0;             \
            au.h[4 + j] = __float2bfloat16(t + (b - t) * f1);                  \
        }                                                                      \
        const int kk = ((N) << 5) + (cq << 3);                                 \
        bf16x8 b0 = *reinterpret_cast<const bf16x8*>(&sW[row][kk]);            \
        bf16x8 b1 = *reinterpret_cast<const bf16x8*>(&sW[row + 16][kk]);       \
        acc0 = __builtin_amdgcn_mfma_f32_16x16x32_bf16(au.v, b0, acc0, 0, 0, 0); \
        acc1 = __builtin_amdgcn_mfma_f32_16x16x32_bf16(au.v, b1, acc1, 0, 0, 0); \
    }

    ISSUE(0, 0)
    ISSUE(1, 1)
    #pragma unroll
    for (int n = 0; n < 9; ++n) {
        // FIFO: 16 outstanding; vmcnt(8) -> point n complete, n+1 in flight.
        if (n < 8) { asm volatile("s_waitcnt vmcnt(8)" ::: "memory"); }
        else       { asm volatile("s_waitcnt vmcnt(0)" ::: "memory"); }
        __builtin_amdgcn_sched_barrier(0);   // rule #18: pin consumers below waitcnt
        CONSUME(n & 1, n)
        if (n < 7) { ISSUE(n & 1, n + 2) }   // refill the slot just consumed
    }
#undef ISSUE
#undef CONSUME
#undef GLD0
#undef GLD1

    // ---- epilogue: C/D layout col=lane&15, row=(lane>>4)*4+i (R4-verified) ----
    const float bias0 = bias[row];
    const float bias1 = bias[row + 16];
    const int rbase = (wave << 4) + (cq << 2);
    #pragma unroll
    for (int i = 0; i < 4; ++i) {
        float* op = out + (size_t)(pix0 + rbase + i) * NO;
        op[row]      = acc0[i] + bias0;
        op[row + 16] = acc1[i] + bias1;
    }
}

extern "C" void kernel_launch(void* const* d_in, const int* in_sizes, int n_in,
                              void* d_out, int out_size, void* d_ws, size_t ws_size,
                              hipStream_t stream) {
    const float* x    = (const float*)d_in[0];
    const float* off  = (const float*)d_in[1];
    const float* Wsrc = (const float*)d_in[2];
    const float* bias = (const float*)d_in[3];
    float* out = (float*)d_out;
    const int npix = NB * NH * NWID;          // 131072
    dcn_kernel<<<npix / PB, 256, 0, stream>>>(x, off, Wsrc, bias, out);
}